// Round 1
// baseline (128.233 us; speedup 1.0000x reference)
//
#include <hip/hip_runtime.h>

#define BB 64
#define SS 2048
#define DD 128
#define DDV 256
#define NCHUNK 8   // S / 256

// ---------------- Kernel 1: blend[b*S+s] = 0.5*scores1 + 0.5 ----------------
// One 64-lane wave per row; lane reads float2 of q and k (coalesced), tanh,
// dot with w_v, butterfly reduce.
__global__ __launch_bounds__(256) void k_blend(const float* __restrict__ q,
                                               const float* __restrict__ k,
                                               const float* __restrict__ wv,
                                               float* __restrict__ blend,
                                               int nrows) {
    const int wave = threadIdx.x >> 6;
    const int lane = threadIdx.x & 63;
    const int row  = blockIdx.x * 4 + wave;
    if (row >= nrows) return;
    const float2 q2 = *(const float2*)(q + (size_t)row * DD + lane * 2);
    const float2 k2 = *(const float2*)(k + (size_t)row * DD + lane * 2);
    const float2 wq = *(const float2*)(wv + lane * 2);
    const float2 wk = *(const float2*)(wv + DD + lane * 2);
    float acc = tanhf(q2.x) * wq.x + tanhf(q2.y) * wq.y
              + tanhf(k2.x) * wk.x + tanhf(k2.y) * wk.y;
#pragma unroll
    for (int off = 32; off; off >>= 1) acc += __shfl_xor(acc, off, 64);
    if (lane == 0) blend[row] = 0.5f * acc + 0.5f;
}

// ---------------- Kernel 2: double softmax -> attention weights ----------------
// One block per batch. scores = softmax(blend) over all S; then masked softmax
// of the scores over s < valid_len. Writes weights in-place over blend.
__global__ __launch_bounds__(256) void k_weights(float* __restrict__ blend,
                                                 const int* __restrict__ valid) {
    __shared__ float sv[SS];     // 8 KB
    __shared__ float red[256];
    const int b = blockIdx.x;
    const int t = threadIdx.x;
    float* rowp = blend + (size_t)b * SS;

    // load + local max
    float lmax = -1e30f;
#pragma unroll
    for (int i = 0; i < 8; i++) {
        float v = rowp[t + i * 256];
        sv[t + i * 256] = v;
        lmax = fmaxf(lmax, v);
    }
    red[t] = lmax; __syncthreads();
    for (int o = 128; o; o >>= 1) { if (t < o) red[t] = fmaxf(red[t], red[t + o]); __syncthreads(); }
    const float m1 = red[0];
    __syncthreads();

    // exp + sum
    float lsum = 0.f;
#pragma unroll
    for (int i = 0; i < 8; i++) {
        float e = expf(sv[t + i * 256] - m1);
        sv[t + i * 256] = e;
        lsum += e;
    }
    red[t] = lsum; __syncthreads();
    for (int o = 128; o; o >>= 1) { if (t < o) red[t] += red[t + o]; __syncthreads(); }
    const float invZ1 = 1.f / red[0];
    __syncthreads();

    // normalized scores
#pragma unroll
    for (int i = 0; i < 8; i++) sv[t + i * 256] *= invZ1;
    __syncthreads();

    const int L = valid[b];

    // masked max over s < L
    float lmax2 = -1e30f;
#pragma unroll
    for (int i = 0; i < 8; i++) {
        int s = t + i * 256;
        if (s < L) lmax2 = fmaxf(lmax2, sv[s]);
    }
    red[t] = lmax2; __syncthreads();
    for (int o = 128; o; o >>= 1) { if (t < o) red[t] = fmaxf(red[t], red[t + o]); __syncthreads(); }
    const float m2 = red[0];
    __syncthreads();

    // masked exp-sum
    float lsum2 = 0.f;
    float ebuf[8];
#pragma unroll
    for (int i = 0; i < 8; i++) {
        int s = t + i * 256;
        float e = (s < L) ? expf(sv[s] - m2) : 0.f;
        ebuf[i] = e;
        lsum2 += e;
    }
    red[t] = lsum2; __syncthreads();
    for (int o = 128; o; o >>= 1) { if (t < o) red[t] += red[t + o]; __syncthreads(); }
    const float invZ2 = 1.f / red[0];

    // final weights (exact 0 for invalid rows)
#pragma unroll
    for (int i = 0; i < 8; i++) rowp[t + i * 256] = ebuf[i] * invZ2;
}

// ---------------- Kernel 3: partial PV sums over s-chunks ----------------
// grid (NCHUNK, B), 256 threads = one v column each. Skips rows with weight
// exactly 0 (uniform branch -> saves HBM reads of invalid value rows).
__global__ __launch_bounds__(256) void k_pv(const float* __restrict__ w,
                                            const float* __restrict__ values,
                                            float* __restrict__ partial) {
    const int c = blockIdx.x, b = blockIdx.y, t = threadIdx.x;
    __shared__ float wsm[256];
    wsm[t] = w[(size_t)b * SS + c * 256 + t];
    __syncthreads();
    const float* vb = values + ((size_t)b * SS + (size_t)c * 256) * DDV + t;
    float acc = 0.f;
    for (int i = 0; i < 256; i++) {
        float wi = wsm[i];
        if (wi != 0.f) acc += wi * vb[(size_t)i * DDV];
    }
    partial[((size_t)b * NCHUNK + c) * 256 + t] = acc;
}

// ---------------- Kernel 4: reduce partials -> out ----------------
__global__ __launch_bounds__(256) void k_reduce(const float* __restrict__ partial,
                                                float* __restrict__ out) {
    const int b = blockIdx.x, t = threadIdx.x;
    float acc = 0.f;
#pragma unroll
    for (int c = 0; c < NCHUNK; c++) acc += partial[((size_t)b * NCHUNK + c) * 256 + t];
    out[(size_t)b * 256 + t] = acc;
}

extern "C" void kernel_launch(void* const* d_in, const int* in_sizes, int n_in,
                              void* d_out, int out_size, void* d_ws, size_t ws_size,
                              hipStream_t stream) {
    const float* q     = (const float*)d_in[0];
    const float* k     = (const float*)d_in[1];
    const float* v     = (const float*)d_in[2];
    const int*   vlen  = (const int*)d_in[3];
    const float* wv    = (const float*)d_in[4];
    // d_in[5..7] (w2, w_v2_w, w_v2_b) are dead: softmax over singleton axis == 1.

    float* blend   = (float*)d_ws;                          // B*S floats
    float* partial = blend + (size_t)BB * SS;               // B*NCHUNK*256 floats
    float* out     = (float*)d_out;

    const int nrows = BB * SS;
    k_blend<<<dim3(nrows / 4), dim3(256), 0, stream>>>(q, k, wv, blend, nrows);
    k_weights<<<dim3(BB), dim3(256), 0, stream>>>(blend, vlen);
    k_pv<<<dim3(NCHUNK, BB), dim3(256), 0, stream>>>(blend, v, partial);
    k_reduce<<<dim3(BB), dim3(256), 0, stream>>>(partial, out);
}

// Round 2
// 56.751 us; speedup vs baseline: 2.2596x; 2.2596x over previous
//
#include <hip/hip_runtime.h>

#define BB 64
#define SS 2048
#define DD 128
#define DDV 256
#define NCH 32          // S / 64 chunks for PV
#define RPC 64          // rows per chunk

// ---------------- Kernel 1: blend[b*S+s] = 0.5*scores1 + 0.5 ----------------
// One 64-lane wave per row. Lanes 0-31 handle the q half, lanes 32-63 the k
// half; each lane loads one float4. wv index is wv[lane*4] for both halves
// (first 128 weights are q's, next 128 are k's).
__global__ __launch_bounds__(256) void k_blend(const float* __restrict__ q,
                                               const float* __restrict__ k,
                                               const float* __restrict__ wv,
                                               float* __restrict__ blend,
                                               int nrows) {
    const int wave = threadIdx.x >> 6;
    const int lane = threadIdx.x & 63;
    const int row  = blockIdx.x * 4 + wave;
    if (row >= nrows) return;
    const float* src = (lane < 32) ? q : k;
    const float4 x  = *(const float4*)(src + (size_t)row * DD + (lane & 31) * 4);
    const float4 w4 = *(const float4*)(wv + lane * 4);
    float acc = tanhf(x.x) * w4.x + tanhf(x.y) * w4.y
              + tanhf(x.z) * w4.z + tanhf(x.w) * w4.w;
#pragma unroll
    for (int off = 32; off; off >>= 1) acc += __shfl_xor(acc, off, 64);
    if (lane == 0) blend[row] = 0.5f * acc + 0.5f;
}

// ---------------- Kernel 2: double softmax -> attention weights ----------------
// One block per batch. scores = softmax(blend) over all S; then masked softmax
// of the scores over s < valid_len. Writes weights in-place over blend.
__global__ __launch_bounds__(256) void k_weights(float* __restrict__ blend,
                                                 const int* __restrict__ valid) {
    __shared__ float sv[SS];
    __shared__ float red[256];
    const int b = blockIdx.x;
    const int t = threadIdx.x;
    float* rowp = blend + (size_t)b * SS;

    float lmax = -1e30f;
#pragma unroll
    for (int i = 0; i < 8; i++) {
        float v = rowp[t + i * 256];
        sv[t + i * 256] = v;
        lmax = fmaxf(lmax, v);
    }
    red[t] = lmax; __syncthreads();
    for (int o = 128; o; o >>= 1) { if (t < o) red[t] = fmaxf(red[t], red[t + o]); __syncthreads(); }
    const float m1 = red[0];
    __syncthreads();

    float lsum = 0.f;
#pragma unroll
    for (int i = 0; i < 8; i++) {
        float e = expf(sv[t + i * 256] - m1);
        sv[t + i * 256] = e;
        lsum += e;
    }
    red[t] = lsum; __syncthreads();
    for (int o = 128; o; o >>= 1) { if (t < o) red[t] += red[t + o]; __syncthreads(); }
    const float invZ1 = 1.f / red[0];
    __syncthreads();

#pragma unroll
    for (int i = 0; i < 8; i++) sv[t + i * 256] *= invZ1;
    __syncthreads();

    const int L = valid[b];

    float lmax2 = -1e30f;
#pragma unroll
    for (int i = 0; i < 8; i++) {
        int s = t + i * 256;
        if (s < L) lmax2 = fmaxf(lmax2, sv[s]);
    }
    red[t] = lmax2; __syncthreads();
    for (int o = 128; o; o >>= 1) { if (t < o) red[t] = fmaxf(red[t], red[t + o]); __syncthreads(); }
    const float m2 = red[0];
    __syncthreads();

    float lsum2 = 0.f;
    float ebuf[8];
#pragma unroll
    for (int i = 0; i < 8; i++) {
        int s = t + i * 256;
        float e = (s < L) ? expf(sv[s] - m2) : 0.f;
        ebuf[i] = e;
        lsum2 += e;
    }
    red[t] = lsum2; __syncthreads();
    for (int o = 128; o; o >>= 1) { if (t < o) red[t] += red[t + o]; __syncthreads(); }
    const float invZ2 = 1.f / red[0];

#pragma unroll
    for (int i = 0; i < 8; i++) rowp[t + i * 256] = ebuf[i] * invZ2;
}

// ---------------- Kernel 3: partial PV sums ----------------
// grid (NCH, B), 256 threads. Wave w owns rows [w*16, w*16+16); each lane
// owns a float4 column slice -> 16 unrolled unconditional float4 loads,
// predicated by weight VALUE (not by load). Block early-outs (writing a zero
// partial) when the whole chunk is past valid_len.
__global__ __launch_bounds__(256) void k_pv(const float* __restrict__ w,
                                            const float* __restrict__ values,
                                            const int* __restrict__ valid,
                                            float* __restrict__ partial) {
    const int c = blockIdx.x, b = blockIdx.y;
    const int t = threadIdx.x;
    const int wid = t >> 6, lane = t & 63;
    const int s0 = c * RPC;
    __shared__ float wsm[RPC];
    __shared__ float4 sacc[256];

    const int L = valid[b];
    float4 acc = {0.f, 0.f, 0.f, 0.f};
    if (s0 < L) {
        if (t < RPC) wsm[t] = w[(size_t)b * SS + s0 + t];
        __syncthreads();
        float wr[16];
        bool any = false;
#pragma unroll
        for (int i = 0; i < 16; i++) { wr[i] = wsm[wid * 16 + i]; any |= (wr[i] != 0.f); }
        if (any) {
            const float* vb = values + ((size_t)b * SS + s0 + wid * 16) * DDV + lane * 4;
#pragma unroll
            for (int i = 0; i < 16; i++) {
                const float4 v4 = *(const float4*)(vb + (size_t)i * DDV);
                acc.x += wr[i] * v4.x;
                acc.y += wr[i] * v4.y;
                acc.z += wr[i] * v4.z;
                acc.w += wr[i] * v4.w;
            }
        }
        __syncthreads();   // wsm reuse safety (none, but keep block converged)
    }
    sacc[t] = acc;
    __syncthreads();
    if (t < 64) {
        const float4 a0 = sacc[t], a1 = sacc[t + 64], a2 = sacc[t + 128], a3 = sacc[t + 192];
        float4 r;
        r.x = a0.x + a1.x + a2.x + a3.x;
        r.y = a0.y + a1.y + a2.y + a3.y;
        r.z = a0.z + a1.z + a2.z + a3.z;
        r.w = a0.w + a1.w + a2.w + a3.w;
        *(float4*)(partial + ((size_t)(b * NCH + c)) * 256 + t * 4) = r;
    }
}

// ---------------- Kernel 4: reduce partials -> out ----------------
__global__ __launch_bounds__(256) void k_reduce(const float* __restrict__ partial,
                                                float* __restrict__ out) {
    const int b = blockIdx.x, t = threadIdx.x;
    float acc = 0.f;
#pragma unroll
    for (int c = 0; c < NCH; c++) acc += partial[((size_t)b * NCH + c) * 256 + t];
    out[(size_t)b * 256 + t] = acc;
}

extern "C" void kernel_launch(void* const* d_in, const int* in_sizes, int n_in,
                              void* d_out, int out_size, void* d_ws, size_t ws_size,
                              hipStream_t stream) {
    const float* q    = (const float*)d_in[0];
    const float* k    = (const float*)d_in[1];
    const float* v    = (const float*)d_in[2];
    const int*   vlen = (const int*)d_in[3];
    const float* wv   = (const float*)d_in[4];
    // d_in[5..7] (w2, w_v2_w, w_v2_b) are dead: softmax over singleton axis == 1.

    float* blend   = (float*)d_ws;                 // B*S floats        (512 KB)
    float* partial = blend + (size_t)BB * SS;      // B*NCH*256 floats  (2 MB)
    float* out     = (float*)d_out;

    const int nrows = BB * SS;
    k_blend <<<dim3(nrows / 4), dim3(256), 0, stream>>>(q, k, wv, blend, nrows);
    k_weights<<<dim3(BB),       dim3(256), 0, stream>>>(blend, vlen);
    k_pv     <<<dim3(NCH, BB),  dim3(256), 0, stream>>>(blend, v, vlen, partial);
    k_reduce <<<dim3(BB),       dim3(256), 0, stream>>>(partial, out);
}

// Round 3
// 55.571 us; speedup vs baseline: 2.3076x; 1.0212x over previous
//
#include <hip/hip_runtime.h>

#define BB 64
#define SS 2048
#define DD 128
#define DDV 256
#define NCH 32          // S / 64 chunks for PV
#define RPC 64          // rows per chunk

// ---------------- Kernel 1: blend[b*S+s] = 0.5*scores1 + 0.5 ----------------
// One 64-lane wave per row. Lanes 0-31 handle the q half, lanes 32-63 the k
// half; each lane loads one float4. wv index is wv[lane*4] for both halves
// (first 128 weights are q's, next 128 are k's).
__global__ __launch_bounds__(256) void k_blend(const float* __restrict__ q,
                                               const float* __restrict__ k,
                                               const float* __restrict__ wv,
                                               float* __restrict__ blend,
                                               int nrows) {
    const int wave = threadIdx.x >> 6;
    const int lane = threadIdx.x & 63;
    const int row  = blockIdx.x * 4 + wave;
    if (row >= nrows) return;
    const float* src = (lane < 32) ? q : k;
    const float4 x  = *(const float4*)(src + (size_t)row * DD + (lane & 31) * 4);
    const float4 w4 = *(const float4*)(wv + lane * 4);
    float acc = tanhf(x.x) * w4.x + tanhf(x.y) * w4.y
              + tanhf(x.z) * w4.z + tanhf(x.w) * w4.w;
#pragma unroll
    for (int off = 32; off; off >>= 1) acc += __shfl_xor(acc, off, 64);
    if (lane == 0) blend[row] = 0.5f * acc + 0.5f;
}

// ---------------- Kernel 2: double softmax -> attention weights ----------------
// One block of 1024 per batch; 2 elements/thread held in registers.
// Reductions: 6-step wave butterfly + 16-entry LDS cross-wave combine.
// Only 4 __syncthreads total. Writes weights in-place over blend
// (exact 0 for s >= valid_len).
__global__ __launch_bounds__(1024) void k_weights(float* __restrict__ blend,
                                                  const int* __restrict__ valid) {
    __shared__ float r0[16], r1[16], r2[16], r3[16];
    const int b = blockIdx.x;
    const int t = threadIdx.x;
    const int wid = t >> 6, lane = t & 63;
    float* rowp = blend + (size_t)b * SS;

    const float v0 = rowp[t];
    const float v1 = rowp[t + 1024];

    // ---- softmax #1 max ----
    float m = fmaxf(v0, v1);
#pragma unroll
    for (int o = 32; o; o >>= 1) m = fmaxf(m, __shfl_xor(m, o, 64));
    if (lane == 0) r0[wid] = m;
    __syncthreads();
    float m1 = r0[0];
#pragma unroll
    for (int i = 1; i < 16; i++) m1 = fmaxf(m1, r0[i]);

    // ---- softmax #1 sum ----
    const float e0 = expf(v0 - m1), e1 = expf(v1 - m1);
    float s = e0 + e1;
#pragma unroll
    for (int o = 32; o; o >>= 1) s += __shfl_xor(s, o, 64);
    if (lane == 0) r1[wid] = s;
    __syncthreads();
    float Z1 = 0.f;
#pragma unroll
    for (int i = 0; i < 16; i++) Z1 += r1[i];
    const float invZ1 = 1.f / Z1;
    const float p0 = e0 * invZ1, p1 = e1 * invZ1;

    const int L = valid[b];

    // ---- masked softmax #2 max (L >= 1, so index 0 always valid) ----
    float mm = -1e30f;
    if (t < L)        mm = p0;
    if (t + 1024 < L) mm = fmaxf(mm, p1);
#pragma unroll
    for (int o = 32; o; o >>= 1) mm = fmaxf(mm, __shfl_xor(mm, o, 64));
    if (lane == 0) r2[wid] = mm;
    __syncthreads();
    float m2 = r2[0];
#pragma unroll
    for (int i = 1; i < 16; i++) m2 = fmaxf(m2, r2[i]);

    // ---- masked softmax #2 sum ----
    const float f0 = (t < L)        ? expf(p0 - m2) : 0.f;
    const float f1 = (t + 1024 < L) ? expf(p1 - m2) : 0.f;
    float s2 = f0 + f1;
#pragma unroll
    for (int o = 32; o; o >>= 1) s2 += __shfl_xor(s2, o, 64);
    if (lane == 0) r3[wid] = s2;
    __syncthreads();
    float Z2 = 0.f;
#pragma unroll
    for (int i = 0; i < 16; i++) Z2 += r3[i];
    const float invZ2 = 1.f / Z2;

    rowp[t]        = f0 * invZ2;
    rowp[t + 1024] = f1 * invZ2;
}

// ---------------- Kernel 3: partial PV sums ----------------
// grid (NCH, B), 256 threads. Wave w owns rows [w*16, w*16+16); each lane
// owns a float4 column slice -> 16 unrolled unconditional float4 loads,
// predicated by weight VALUE (not by load). Block early-outs (writing a zero
// partial) when the whole chunk is past valid_len.
__global__ __launch_bounds__(256) void k_pv(const float* __restrict__ w,
                                            const float* __restrict__ values,
                                            const int* __restrict__ valid,
                                            float* __restrict__ partial) {
    const int c = blockIdx.x, b = blockIdx.y;
    const int t = threadIdx.x;
    const int wid = t >> 6, lane = t & 63;
    const int s0 = c * RPC;
    __shared__ float wsm[RPC];
    __shared__ float4 sacc[256];

    const int L = valid[b];
    float4 acc = {0.f, 0.f, 0.f, 0.f};
    if (s0 < L) {
        if (t < RPC) wsm[t] = w[(size_t)b * SS + s0 + t];
        __syncthreads();
        float wr[16];
        bool any = false;
#pragma unroll
        for (int i = 0; i < 16; i++) { wr[i] = wsm[wid * 16 + i]; any |= (wr[i] != 0.f); }
        if (any) {
            const float* vb = values + ((size_t)b * SS + s0 + wid * 16) * DDV + lane * 4;
#pragma unroll
            for (int i = 0; i < 16; i++) {
                const float4 v4 = *(const float4*)(vb + (size_t)i * DDV);
                acc.x += wr[i] * v4.x;
                acc.y += wr[i] * v4.y;
                acc.z += wr[i] * v4.z;
                acc.w += wr[i] * v4.w;
            }
        }
    }
    sacc[t] = acc;
    __syncthreads();
    if (t < 64) {
        const float4 a0 = sacc[t], a1 = sacc[t + 64], a2 = sacc[t + 128], a3 = sacc[t + 192];
        float4 r;
        r.x = a0.x + a1.x + a2.x + a3.x;
        r.y = a0.y + a1.y + a2.y + a3.y;
        r.z = a0.z + a1.z + a2.z + a3.z;
        r.w = a0.w + a1.w + a2.w + a3.w;
        *(float4*)(partial + ((size_t)(b * NCH + c)) * 256 + t * 4) = r;
    }
}

// ---------------- Kernel 4: reduce partials -> out ----------------
__global__ __launch_bounds__(256) void k_reduce(const float* __restrict__ partial,
                                                float* __restrict__ out) {
    const int b = blockIdx.x, t = threadIdx.x;
    float acc = 0.f;
#pragma unroll
    for (int c = 0; c < NCH; c++) acc += partial[((size_t)b * NCH + c) * 256 + t];
    out[(size_t)b * 256 + t] = acc;
}

extern "C" void kernel_launch(void* const* d_in, const int* in_sizes, int n_in,
                              void* d_out, int out_size, void* d_ws, size_t ws_size,
                              hipStream_t stream) {
    const float* q    = (const float*)d_in[0];
    const float* k    = (const float*)d_in[1];
    const float* v    = (const float*)d_in[2];
    const int*   vlen = (const int*)d_in[3];
    const float* wv   = (const float*)d_in[4];
    // d_in[5..7] (w2, w_v2_w, w_v2_b) are dead: softmax over singleton axis == 1.

    float* blend   = (float*)d_ws;                 // B*S floats        (512 KB)
    float* partial = blend + (size_t)BB * SS;      // B*NCH*256 floats  (2 MB)
    float* out     = (float*)d_out;

    const int nrows = BB * SS;
    k_blend <<<dim3(nrows / 4), dim3(256),  0, stream>>>(q, k, wv, blend, nrows);
    k_weights<<<dim3(BB),       dim3(1024), 0, stream>>>(blend, vlen);
    k_pv     <<<dim3(NCH, BB),  dim3(256),  0, stream>>>(blend, v, vlen, partial);
    k_reduce <<<dim3(BB),       dim3(256),  0, stream>>>(partial, out);
}